// Round 2
// baseline (312.742 us; speedup 1.0000x reference)
//
#include <hip/hip_runtime.h>
#include <hip/hip_bf16.h>

// SlicingLinearBlock: out[16384,4096] = x[16384,256] @ B[256,4096] (fp32),
// where B[k,o] = W[k/8, o, k%8].  Strategy: pre-convert x and W to bf16 in
// d_ws (one merged prep kernel), then 128x128 bf16 MFMA GEMM:
//   BK=32, double-buffered LDS (32 KB total -> 4 blocks/CU with VGPR<=128),
//   2-phase prefetch (issue next K-tile's global_load_lds before compute),
//   XCD-contiguous block swizzle (A-slice+B fit per-XCD L2),
//   swapped-operand MFMA -> float4 nontemporal C stores.
//
// Workspace layout (d_ws): [0, 8MB) x_bf16 [16384,256]; [8MB, 10MB) Bt_bf16 [4096,256].

typedef __attribute__((ext_vector_type(8)))  __bf16          bf16x8;
typedef __attribute__((ext_vector_type(8)))  unsigned short  ushort8;
typedef __attribute__((ext_vector_type(4)))  float           floatx4;

__device__ __forceinline__ unsigned short f2bf(float f) {
    union { float f; unsigned u; } v; v.f = f;
    unsigned r = v.u + 0x7fffu + ((v.u >> 16) & 1u);   // RNE
    return (unsigned short)(r >> 16);
}

// Merged prep: blocks [0,2048) convert x (fp32->bf16, 8 elem/thread);
// blocks [2048,2560) pack W [32,4096,8] -> Bt [4096,256] (Bt[o][s*8+c]=W[s][o][c]).
__global__ __launch_bounds__(256) void prep_kernel(
    const float* __restrict__ x, const float* __restrict__ W,
    unsigned short* __restrict__ xb, unsigned short* __restrict__ wb) {
    const int b = blockIdx.x;
    if (b < 2048) {
        const int t = b * 256 + threadIdx.x;           // 524288 threads
        const float4* p = (const float4*)x;
        float4 a = p[2 * t], c = p[2 * t + 1];
        ushort8 v;
        v[0] = f2bf(a.x); v[1] = f2bf(a.y); v[2] = f2bf(a.z); v[3] = f2bf(a.w);
        v[4] = f2bf(c.x); v[5] = f2bf(c.y); v[6] = f2bf(c.z); v[7] = f2bf(c.w);
        *(ushort8*)(xb + (size_t)t * 8) = v;
    } else {
        const int t = (b - 2048) * 256 + threadIdx.x;  // 131072 threads
        const int s = t >> 12;                         // 0..31
        const int o = t & 4095;
        const float4* p = (const float4*)(W + (size_t)s * 32768 + (size_t)o * 8);
        float4 a = p[0], c = p[1];
        ushort8 v;
        v[0] = f2bf(a.x); v[1] = f2bf(a.y); v[2] = f2bf(a.z); v[3] = f2bf(a.w);
        v[4] = f2bf(c.x); v[5] = f2bf(c.y); v[6] = f2bf(c.z); v[7] = f2bf(c.w);
        *(ushort8*)(wb + (size_t)o * 256 + (size_t)s * 8) = v;
    }
}

__device__ __forceinline__ void gload_lds16(const unsigned short* g, unsigned short* l) {
    __builtin_amdgcn_global_load_lds(
        (const __attribute__((address_space(1))) unsigned int*)(const void*)g,
        (__attribute__((address_space(3))) unsigned int*)(void*)l,
        16, 0, 0);
}

// C[M=16384, N=4096] fp32 = A[M,256]bf16 * Bt[N,256]bf16^T
// 128x128 tile, BK=32 double-buffered, 4 waves 2x2, each wave 64x64 via
// 4x4 of 16x16x32 MFMA (operand-swapped: acc holds C^T fragments so each
// lane owns 4 consecutive output columns -> float4 stores).
__global__ __launch_bounds__(256, 4) void gemm_kernel(
    const unsigned short* __restrict__ A,
    const unsigned short* __restrict__ Bt,
    float* __restrict__ C) {
    // 2 buffers x (128 rows x 32 cols) x bf16 = 8 KB each matrix -> 32 KB total.
    __shared__ __align__(16) unsigned short lsA[2][128 * 32];
    __shared__ __align__(16) unsigned short lsB[2][128 * 32];

    const int tid  = threadIdx.x;
    const int wave = tid >> 6;
    const int lane = tid & 63;

    // --- XCD-contiguous swizzle: HW round-robins flat ids across 8 XCDs;
    // remap so XCD x gets 512 consecutive work-ids = bm chunk [x*16,(x+1)*16),
    // all bn.  Per XCD: 1 MB A-slice + 2 MB B -> fits 4 MB L2.  4096%8==0.
    const int flat = blockIdx.y * 32 + blockIdx.x;
    const int nid  = (flat & 7) * 512 + (flat >> 3);
    const int bm   = nid >> 5;       // 0..127
    const int bn   = nid & 31;       // 0..31

    // --- staging addressing ---
    // K-tile = 128 rows x 32 cols = 4 chunks of 16B per row.  Thread t covers
    // row t>>2, LDS slot t&3 (linear: LDS byte = t*16, wave-uniform base +
    // lane*16 as global_load_lds requires).  Global chunk is pre-swizzled by
    // the row key ((row>>1)&3) so fragment reads can un-swizzle (rule 21):
    // LDS[r][slot] = G[r][slot ^ ((r>>1)&3)].
    const int sr  = tid >> 2;                              // 0..63
    const int gch = (tid & 3) ^ ((tid >> 3) & 3);          // pre-swizzled chunk
    const unsigned short* Ag = A  + ((size_t)(bm * 128 + sr)) * 256 + gch * 8;
    const unsigned short* Bg = Bt + ((size_t)(bn * 128 + sr)) * 256 + gch * 8;
    unsigned short* laW[2] = { &lsA[0][wave * 512], &lsA[1][wave * 512] };
    unsigned short* lbW[2] = { &lsB[0][wave * 512], &lsB[1][wave * 512] };

    // --- fragment addressing ---
    const int wrow = wave >> 1, wcol = wave & 1;
    const int fr = lane & 15;        // A-m / B-n row within 16x16 tile
    const int fq = lane >> 4;        // k-chunk 0..3
    const int so = (fq ^ ((fr >> 1) & 3)) * 8;             // un-swizzled slot
    const unsigned short* aF[2] = { &lsA[0][(wrow * 64 + fr) * 32] + so,
                                    &lsA[1][(wrow * 64 + fr) * 32] + so };
    const unsigned short* bF[2] = { &lsB[0][(wcol * 64 + fr) * 32] + so,
                                    &lsB[1][(wcol * 64 + fr) * 32] + so };

    floatx4 acc[4][4] = {};          // acc[j(n)][i(m)], C^T fragments

    // prologue: stage k-tile 0 into buffer 0
    gload_lds16(Ag,            laW[0]);
    gload_lds16(Ag + 64 * 256, laW[0] + 2048);
    gload_lds16(Bg,            lbW[0]);
    gload_lds16(Bg + 64 * 256, lbW[0] + 2048);
    __syncthreads();

#pragma unroll
    for (int kt = 0; kt < 8; ++kt) {
        const int cur = kt & 1;      // compile-time under full unroll
        // prefetch next k-tile into the other buffer (issued before compute)
        if (kt < 7) {
            const int ko = (kt + 1) * 32;
            gload_lds16(Ag + ko,            laW[cur ^ 1]);
            gload_lds16(Ag + ko + 64 * 256, laW[cur ^ 1] + 2048);
            gload_lds16(Bg + ko,            lbW[cur ^ 1]);
            gload_lds16(Bg + ko + 64 * 256, lbW[cur ^ 1] + 2048);
        }

        bf16x8 af[4], bv[4];
#pragma unroll
        for (int i = 0; i < 4; ++i) {
            af[i] = *(const bf16x8*)(const void*)(aF[cur] + i * 512);
            bv[i] = *(const bf16x8*)(const void*)(bF[cur] + i * 512);
        }
#pragma unroll
        for (int j = 0; j < 4; ++j)
#pragma unroll
            for (int i = 0; i < 4; ++i)
                acc[j][i] = __builtin_amdgcn_mfma_f32_16x16x32_bf16(
                    bv[j], af[i], acc[j][i], 0, 0, 0);
        __syncthreads();             // drains vmcnt(0): prefetched tile landed
    }

    // --- epilogue ---
    // Swapped operands: D[n][m]; C/D layout col=lane&15, row=(lane>>4)*4+reg
    // => m = fr, n = fq*4 + reg.  Each lane owns 4 consecutive output columns
    // -> one nontemporal dwordx4 per (i,j); C is never re-read, keep it out
    // of L2 so A/B stay resident.
    const int row0 = bm * 128 + wrow * 64 + fr;        // output row (m)
    const int col0 = bn * 128 + wcol * 64 + fq * 4;    // output col base (n)
#pragma unroll
    for (int i = 0; i < 4; ++i) {
        float* Cp = C + (size_t)(row0 + i * 16) * 4096 + col0;
#pragma unroll
        for (int j = 0; j < 4; ++j)
            __builtin_nontemporal_store(acc[j][i], (floatx4*)(Cp + j * 16));
    }
}

extern "C" void kernel_launch(void* const* d_in, const int* in_sizes, int n_in,
                              void* d_out, int out_size, void* d_ws, size_t ws_size,
                              hipStream_t stream) {
    const float* x = (const float*)d_in[0];   // [16384, 256]
    const float* W = (const float*)d_in[1];   // [32, 4096, 8]
    float* out = (float*)d_out;               // [16384, 4096]

    unsigned short* xb = (unsigned short*)d_ws;            // 8 MB
    unsigned short* wb = xb + (size_t)16384 * 256;         // +2 MB = 10 MB total

    prep_kernel<<<2560, 256, 0, stream>>>(x, W, xb, wb);

    dim3 grid(32, 128);   // bn = 4096/128, bm = 16384/128
    gemm_kernel<<<grid, 256, 0, stream>>>(xb, wb, out);
}